// Round 1
// baseline (313.208 us; speedup 1.0000x reference)
//
#include <hip/hip_runtime.h>
#include <hip/hip_bf16.h>
#include <stdint.h>

typedef __attribute__((ext_vector_type(8))) __bf16 bf16x8;
typedef __attribute__((ext_vector_type(4))) float f32x4;

constexpr int K_DIM = 4096;
constexpr int N_DIM = 11008;
constexpr int M_DIM = 256;   // B*S
constexpr int TN = 32;       // N cols per block
constexpr int BK = 64;       // K per tile
constexpr int NT = 256;      // threads (4 waves, each owns 64 M-rows x 32 N-cols)
constexpr int KT_ALL = K_DIM / BK;   // 64
constexpr int KSPLIT = 3;    // grid = 344*3 = 1032 ~= 4 blocks/CU * 256 CU capacity

__device__ __forceinline__ bf16x8 cvt8(const float4 u0, const float4 u1) {
  bf16x8 v;
  v[0] = (__bf16)u0.x; v[1] = (__bf16)u0.y; v[2] = (__bf16)u0.z; v[3] = (__bf16)u0.w;
  v[4] = (__bf16)u1.x; v[5] = (__bf16)u1.y; v[6] = (__bf16)u1.z; v[7] = (__bf16)u1.w;
  return v;
}

// Repack x fp32 [256][4096] -> xws bf16 [K/8][256][8] (fragment-major).
// A-frag loads in the GEMM then cover 4x256B dense segments (quad-major, 16 rows
// contiguous), fully coalesced and L2-resident. Writes here are fully coalesced;
// reads are 32B-granule strided (x fp32 is 4 MB, L2-absorbs).
__global__ void cvt_x_kernel(const float* __restrict__ x, __bf16* __restrict__ ws) {
  const int t = blockIdx.x * 256 + threadIdx.x;   // t = k8*256 + m
  const int m = t & 255;
  const int k8 = t >> 8;
  const float* src = x + (size_t)m * K_DIM + k8 * 8;
  const float4 u0 = ((const float4*)src)[0];
  const float4 u1 = ((const float4*)src)[1];
  *(bf16x8*)(ws + (size_t)t * 8) = cvt8(u0, u1);
}

template<bool USE_WS>
__global__ __launch_bounds__(NT, 4) void int8_linear_kernel(
    const float* __restrict__ x,     // [256,4096] fp32 (fallback path)
    const __bf16* __restrict__ xws,  // [512][256][8] bf16 frag-major (fast path)
    const int*   __restrict__ w,     // [11008,4096] int32 (int8 widened)
    const float* __restrict__ scale, // [11008]
    const float* __restrict__ bias,  // [11008]
    float*       __restrict__ out)   // [256,11008] fp32, pre-zeroed, atomic-accumulated
{
  // W only in LDS (shared by all 4 waves -> W read once from L2/HBM per block).
  // XOR chunk swizzle (slot = chunk ^ (row&7)) keeps ds_read_b128 conflict-free.
  __shared__ __bf16 Ws[2][TN * BK];   // 2 x 4 KB  -> residency is VGPR-bound, not LDS

  const int tid  = threadIdx.x;
  const int lane = tid & 63;
  const int wv   = tid >> 6;
  const int quad = lane >> 4;
  const int l16  = lane & 15;
  const int n_base = blockIdx.x * TN;
  const int kc     = blockIdx.y;

  // split-K tile range: {21,21,22} tiles of BK=64
  const int t0 = (kc * KT_ALL) / KSPLIT;
  const int t1 = ((kc + 1) * KT_ALL) / KSPLIT;
  const int ntile = t1 - t0;
  const int k0 = t0 * BK;

  // W staging: thread owns 8 int32 (chunk wc) of row wrow
  const int wrow  = tid >> 3;
  const int wc    = tid & 7;
  const int wslot = wc ^ (wrow & 7);
  const int* wptr = w + (int64_t)(n_base + wrow) * K_DIM + k0 + wc * 8;

  // A lane pointer (fast path): element = k8*2048 + m*8, k8 = k0/8 + t*8 + ks*4 + quad
  const __bf16* aptr = xws + (size_t)(k0 / 8 + quad) * (M_DIM * 8) + (wv * 64 + l16) * 8;
  // fallback: row-major fp32
  const float* fptr = x + (int64_t)(wv * 64 + l16) * K_DIM + k0 + quad * 8;

  f32x4 acc[4][2];
#pragma unroll
  for (int i = 0; i < 4; ++i)
#pragma unroll
    for (int j = 0; j < 2; ++j) acc[i][j] = (f32x4){0.f, 0.f, 0.f, 0.f};

  int wr0[8], wr1[8];
  auto wload = [&](int t, int* wr) {
    const int4* p = (const int4*)(wptr + t * BK);
    const int4 u0 = p[0], u1 = p[1];
    wr[0] = u0.x; wr[1] = u0.y; wr[2] = u0.z; wr[3] = u0.w;
    wr[4] = u1.x; wr[5] = u1.y; wr[6] = u1.z; wr[7] = u1.w;
  };
  auto commitW = [&](const int* wr, __bf16* wbuf) {
    bf16x8 v;
#pragma unroll
    for (int j = 0; j < 8; ++j) v[j] = (__bf16)(float)wr[j];
    *(bf16x8*)(wbuf + wrow * BK + wslot * 8) = v;
  };
  auto compute = [&](int t, const __bf16* wbuf) {
    bf16x8 a[2][4], b[2][2];
    if (USE_WS) {
#pragma unroll
      for (int ks = 0; ks < 2; ++ks)
#pragma unroll
        for (int mi = 0; mi < 4; ++mi)
          a[ks][mi] = *(const bf16x8*)(aptr + (size_t)(t * 8 + ks * 4) * (M_DIM * 8) + mi * 128);
    } else {
#pragma unroll
      for (int ks = 0; ks < 2; ++ks)
#pragma unroll
        for (int mi = 0; mi < 4; ++mi) {
          const float* s = fptr + (int64_t)mi * 16 * K_DIM + t * BK + ks * 32;
          a[ks][mi] = cvt8(((const float4*)s)[0], ((const float4*)s)[1]);
        }
    }
#pragma unroll
    for (int ks = 0; ks < 2; ++ks)
#pragma unroll
      for (int ni = 0; ni < 2; ++ni) {
        const int n = ni * 16 + l16;
        const int slot = (ks * 4 + quad) ^ (n & 7);
        b[ks][ni] = *(const bf16x8*)(wbuf + n * BK + slot * 8);
      }
#pragma unroll
    for (int ks = 0; ks < 2; ++ks)
#pragma unroll
      for (int mi = 0; mi < 4; ++mi)
#pragma unroll
        for (int ni = 0; ni < 2; ++ni)
          acc[mi][ni] = __builtin_amdgcn_mfma_f32_16x16x32_bf16(
              a[ks][mi], b[ks][ni], acc[mi][ni], 0, 0, 0);
  };

  // Prologue (ntile >= 21 always): tile0 staged, wload(1) in flight
  wload(0, wr0);
  commitW(wr0, Ws[0]);
  wload(1, wr1);

  int t = 0;
  for (; t + 2 <= ntile; t += 2) {
    {  // even phase: Ws[0]
      __syncthreads();
      if (t + 2 < ntile) wload(t + 2, wr0);
      compute(t, Ws[0]);
      commitW(wr1, Ws[1]);               // t+1 < ntile guaranteed here
    }
    {  // odd phase: Ws[1]
      __syncthreads();
      if (t + 3 < ntile) wload(t + 3, wr1);
      compute(t + 1, Ws[1]);
      if (t + 2 < ntile) commitW(wr0, Ws[0]);
    }
  }
  if (t < ntile) {  // odd tail (ntile=21): Ws[0] already committed last odd phase
    __syncthreads();
    compute(t, Ws[0]);
  }

  // Epilogue: C/D layout col=lane&15, row=quad*4+reg (m89-verified).
  // Scale per-partial (linear); bias added exactly once by the kc==0 block.
#pragma unroll
  for (int ni = 0; ni < 2; ++ni) {
    const int col = n_base + ni * 16 + l16;
    const float sc = scale[col];
    const float bi = (kc == 0) ? bias[col] : 0.0f;
#pragma unroll
    for (int mi = 0; mi < 4; ++mi) {
      const int row0 = wv * 64 + mi * 16 + quad * 4;
#pragma unroll
      for (int r = 0; r < 4; ++r)
        unsafeAtomicAdd(out + (int64_t)(row0 + r) * N_DIM + col,
                        acc[mi][ni][r] * sc + bi);
    }
  }
}

extern "C" void kernel_launch(void* const* d_in, const int* in_sizes, int n_in,
                              void* d_out, int out_size, void* d_ws, size_t ws_size,
                              hipStream_t stream) {
  const float* x     = (const float*)d_in[0];
  const int*   w     = (const int*)d_in[1];
  const float* scale = (const float*)d_in[2];
  const float* bias  = (const float*)d_in[3];
  float* out = (float*)d_out;

  __bf16* xws = (__bf16*)d_ws;
  const bool use_ws = ws_size >= (size_t)M_DIM * K_DIM * sizeof(__bf16);

  // split-K partials accumulate via atomics -> zero the output first
  hipMemsetAsync(out, 0, (size_t)M_DIM * N_DIM * sizeof(float), stream);

  dim3 grid(N_DIM / TN, KSPLIT), block(NT);
  if (use_ws) {
    cvt_x_kernel<<<M_DIM * K_DIM / (256 * 8), 256, 0, stream>>>(x, xws);
    int8_linear_kernel<true><<<grid, block, 0, stream>>>(x, xws, w, scale, bias, out);
  } else {
    int8_linear_kernel<false><<<grid, block, 0, stream>>>(x, xws, w, scale, bias, out);
  }
}

// Round 2
// 304.876 us; speedup vs baseline: 1.0273x; 1.0273x over previous
//
#include <hip/hip_runtime.h>
#include <hip/hip_bf16.h>
#include <stdint.h>

typedef __attribute__((ext_vector_type(8))) __bf16 bf16x8;
typedef __attribute__((ext_vector_type(4))) float f32x4;

constexpr int K_DIM = 4096;
constexpr int N_DIM = 11008;
constexpr int M_DIM = 256;   // B*S
constexpr int TN = 32;       // N cols per block
constexpr int BK = 64;       // K per tile
constexpr int NT = 256;      // threads (4 waves, each owns 64 M-rows x 32 N-cols)
constexpr int KT_ALL = K_DIM / BK;   // 64
constexpr int KSPLIT = 3;    // grid = 344*3 = 1032

__device__ __forceinline__ bf16x8 cvt8(const float4 u0, const float4 u1) {
  bf16x8 v;
  v[0] = (__bf16)u0.x; v[1] = (__bf16)u0.y; v[2] = (__bf16)u0.z; v[3] = (__bf16)u0.w;
  v[4] = (__bf16)u1.x; v[5] = (__bf16)u1.y; v[6] = (__bf16)u1.z; v[7] = (__bf16)u1.w;
  return v;
}

// Repack x fp32 [256][4096] -> xws bf16 [K/8][256][8] (fragment-major).
// A-frag loads in the GEMM cover dense 256B segments per 16-lane quad.
__global__ void cvt_x_kernel(const float* __restrict__ x, __bf16* __restrict__ ws) {
  const int t = blockIdx.x * 256 + threadIdx.x;   // t = k8*256 + m
  const int m = t & 255;
  const int k8 = t >> 8;
  const float* src = x + (size_t)m * K_DIM + k8 * 8;
  const float4 u0 = ((const float4*)src)[0];
  const float4 u1 = ((const float4*)src)[1];
  *(bf16x8*)(ws + (size_t)t * 8) = cvt8(u0, u1);
}

template<bool USE_WS>
__global__ __launch_bounds__(NT, 3) void int8_linear_kernel(
    const float* __restrict__ x,     // [256,4096] fp32 (fallback path)
    const __bf16* __restrict__ xws,  // [512][256][8] bf16 frag-major (fast path)
    const int*   __restrict__ w,     // [11008,4096] int32 (int8 widened)
    const float* __restrict__ scale, // [11008]
    const float* __restrict__ bias,  // [11008]
    float*       __restrict__ out)   // [256,11008] fp32, pre-zeroed, atomic-accumulated
{
  // W only in LDS (shared by all 4 waves). XOR chunk swizzle keeps ds_read_b128
  // conflict-free. A goes global->register, double-buffered one tile ahead:
  // per-phase chain is {barrier -> issue t+1 loads -> MFMA(regs t) -> commitW}.
  __shared__ __bf16 Ws[2][TN * BK];   // 2 x 4 KB

  const int tid  = threadIdx.x;
  const int lane = tid & 63;
  const int wv   = tid >> 6;
  const int quad = lane >> 4;
  const int l16  = lane & 15;
  const int n_base = blockIdx.x * TN;
  const int kc     = blockIdx.y;

  // split-K tile range: {21,21,22} tiles of BK=64
  const int t0 = (kc * KT_ALL) / KSPLIT;
  const int t1 = ((kc + 1) * KT_ALL) / KSPLIT;
  const int ntile = t1 - t0;
  const int k0 = t0 * BK;

  // W staging: thread owns 8 int32 (chunk wc) of row wrow
  const int wrow  = tid >> 3;
  const int wc    = tid & 7;
  const int wslot = wc ^ (wrow & 7);
  const int* wptr = w + (int64_t)(n_base + wrow) * K_DIM + k0 + wc * 8;

  // A lane pointer (fast path): elem = k8*2048 + m*8, k8 = k0/8 + t*8 + ks*4 + quad
  const __bf16* aptr = xws + (size_t)(k0 / 8 + quad) * (M_DIM * 8) + (wv * 64 + l16) * 8;
  // fallback: row-major fp32
  const float* fptr = x + (int64_t)(wv * 64 + l16) * K_DIM + k0 + quad * 8;

  f32x4 acc[4][2];
#pragma unroll
  for (int i = 0; i < 4; ++i)
#pragma unroll
    for (int j = 0; j < 2; ++j) acc[i][j] = (f32x4){0.f, 0.f, 0.f, 0.f};

  int wr[8];
  bf16x8 ar0[8], ar1[8];   // A frag regs, [ks*4+mi], double-buffered across phases

  auto wload = [&](int t) {
    const int4* p = (const int4*)(wptr + t * BK);
    const int4 u0 = p[0], u1 = p[1];
    wr[0] = u0.x; wr[1] = u0.y; wr[2] = u0.z; wr[3] = u0.w;
    wr[4] = u1.x; wr[5] = u1.y; wr[6] = u1.z; wr[7] = u1.w;
  };
  auto commitW = [&](__bf16* wbuf) {
    bf16x8 v;
#pragma unroll
    for (int j = 0; j < 8; ++j) v[j] = (__bf16)(float)wr[j];
    *(bf16x8*)(wbuf + wrow * BK + wslot * 8) = v;
  };
  auto aload = [&](int t, bf16x8* ar) {
    if (USE_WS) {
#pragma unroll
      for (int ks = 0; ks < 2; ++ks)
#pragma unroll
        for (int mi = 0; mi < 4; ++mi)
          ar[ks * 4 + mi] =
              *(const bf16x8*)(aptr + (size_t)(t * 8 + ks * 4) * (M_DIM * 8) + mi * 128);
    } else {
#pragma unroll
      for (int ks = 0; ks < 2; ++ks)
#pragma unroll
        for (int mi = 0; mi < 4; ++mi) {
          const float* s = fptr + (int64_t)mi * 16 * K_DIM + t * BK + ks * 32;
          ar[ks * 4 + mi] = cvt8(((const float4*)s)[0], ((const float4*)s)[1]);
        }
    }
  };
  auto compute = [&](const bf16x8* ar, const __bf16* wbuf) {
#pragma unroll
    for (int ks = 0; ks < 2; ++ks) {
      bf16x8 b[2];
#pragma unroll
      for (int ni = 0; ni < 2; ++ni) {
        const int n = ni * 16 + l16;
        const int slot = (ks * 4 + quad) ^ (n & 7);
        b[ni] = *(const bf16x8*)(wbuf + n * BK + slot * 8);
      }
#pragma unroll
      for (int mi = 0; mi < 4; ++mi)
#pragma unroll
        for (int ni = 0; ni < 2; ++ni)
          acc[mi][ni] = __builtin_amdgcn_mfma_f32_16x16x32_bf16(
              ar[ks * 4 + mi], b[ni], acc[mi][ni], 0, 0, 0);
    }
  };

  // Prologue: W tile0 committed to LDS; A tile0 in regs.
  wload(0);
  commitW(Ws[0]);
  aload(0, ar0);

  // One barrier per phase. Phase t: read Ws[t&1] (committed last phase, made
  // visible by this phase's barrier), write Ws[(t&1)^1] (its readers passed
  // the barrier). Loads for t+1 issue BEFORE compute(t) -> latency overlaps
  // the MFMA phase; the pre-barrier vmcnt(0) drain sees mostly-landed loads.
  int t = 0;
  for (; t + 2 <= ntile; t += 2) {
    {  // even phase: tile t from ar0 / Ws[0]
      __syncthreads();
      aload(t + 1, ar1);            // t+1 < ntile guaranteed by loop bound
      wload(t + 1);
      compute(ar0, Ws[0]);
      commitW(Ws[1]);
    }
    {  // odd phase: tile t+1 from ar1 / Ws[1]
      __syncthreads();
      if (t + 2 < ntile) { aload(t + 2, ar0); wload(t + 2); }
      compute(ar1, Ws[1]);
      if (t + 2 < ntile) commitW(Ws[0]);
    }
  }
  if (t < ntile) {  // odd-ntile tail: tile t staged into ar0 / Ws[0] last phase
    __syncthreads();
    compute(ar0, Ws[0]);
  }

  // Epilogue: C/D layout col=lane&15, row=quad*4+reg (m89-verified).
  // Scale per-partial (linear); bias added exactly once by the kc==0 block.
#pragma unroll
  for (int ni = 0; ni < 2; ++ni) {
    const int col = n_base + ni * 16 + l16;
    const float sc = scale[col];
    const float bi = (kc == 0) ? bias[col] : 0.0f;
#pragma unroll
    for (int mi = 0; mi < 4; ++mi) {
      const int row0 = wv * 64 + mi * 16 + quad * 4;
#pragma unroll
      for (int r = 0; r < 4; ++r)
        unsafeAtomicAdd(out + (int64_t)(row0 + r) * N_DIM + col,
                        acc[mi][ni][r] * sc + bi);
    }
  }
}

extern "C" void kernel_launch(void* const* d_in, const int* in_sizes, int n_in,
                              void* d_out, int out_size, void* d_ws, size_t ws_size,
                              hipStream_t stream) {
  const float* x     = (const float*)d_in[0];
  const int*   w     = (const int*)d_in[1];
  const float* scale = (const float*)d_in[2];
  const float* bias  = (const float*)d_in[3];
  float* out = (float*)d_out;

  __bf16* xws = (__bf16*)d_ws;
  const bool use_ws = ws_size >= (size_t)M_DIM * K_DIM * sizeof(__bf16);

  // split-K partials accumulate via atomics -> zero the output first
  hipMemsetAsync(out, 0, (size_t)M_DIM * N_DIM * sizeof(float), stream);

  dim3 grid(N_DIM / TN, KSPLIT), block(NT);
  if (use_ws) {
    cvt_x_kernel<<<M_DIM * K_DIM / (256 * 8), 256, 0, stream>>>(x, xws);
    int8_linear_kernel<true><<<grid, block, 0, stream>>>(x, xws, w, scale, bias, out);
  } else {
    int8_linear_kernel<false><<<grid, block, 0, stream>>>(x, xws, w, scale, bias, out);
  }
}